// Round 21
// baseline (157.752 us; speedup 1.0000x reference)
//
#include <hip/hip_runtime.h>

#define S_LEN 2048
#define D_DIM 2048
#define NHEAD 32
#define NKVH  8
#define HDIM  64
#define NBT   3200   // 2048 q + 512 k + 512 v + 16 fiber + 64 w1h + 48 pad

typedef __attribute__((ext_vector_type(4))) float f32x4;
typedef __attribute__((ext_vector_type(8))) short bf16x8;

__device__ __forceinline__ unsigned short f2bf(float x) {
    union { float f; unsigned u; } v; v.f = x;
    unsigned r = v.u + 0x7FFFu + ((v.u >> 16) & 1u);
    return (unsigned short)(r >> 16);
}

// async global->LDS 16B: dest = wave-uniform base + lane*16
#define GLD(gsrc, ldst) __builtin_amdgcn_global_load_lds( \
    (const __attribute__((address_space(1))) unsigned int*)(const void*)(gsrc), \
    (__attribute__((address_space(3))) unsigned int*)(void*)(ldst), 16, 0, 0)

#define SWZ(r) (((r) & 7) << 4)

// k-permutation: QK^T C-layout -> PV B-frag consumption (verified R13)
#define KPERM(kk) (((kk) & 32) | (((kk) & 12) << 1) | (((kk) & 16) >> 2) | ((kk) & 3))

// ---- generic 64x64 f32->bf16 transpose tile (into row-stride-2048 dest) ----
__device__ __forceinline__ void dev_trans(const float* __restrict__ W, unsigned short* __restrict__ WT,
                                          int N, int k0, int n0, int t, unsigned short L[64][65]) {
    for (int it = 0; it < 16; ++it) {
        int e = it * 256 + t;
        int r = e >> 6, c = e & 63;
        L[c][r] = f2bf(W[(size_t)(k0 + r) * N + n0 + c]);
    }
    __syncthreads();
    for (int it = 0; it < 16; ++it) {
        int e = it * 256 + t;
        int n = e >> 6, kk = e & 63;
        WT[(size_t)(n0 + n) * 2048 + k0 + kk] = L[n][kk];
    }
}

// ---- merged prep: cvt_h + Wq/Wk/Wv/Wo/Wf/W1 transposes + pad zero ----
__global__ __launch_bounds__(256) void k_prep(const float* __restrict__ h, unsigned short* __restrict__ hb,
        const float* __restrict__ Wq, const float* __restrict__ Wk, const float* __restrict__ Wv,
        const float* __restrict__ Wo, const float* __restrict__ Wf, const float* __restrict__ W1,
        unsigned short* __restrict__ bt, unsigned short* __restrict__ wot) {
    __shared__ unsigned short L[64][65];
    int b = blockIdx.x, t = threadIdx.x;
    if (b < 4096) {
        int i = (b * 256 + t) * 4;
        float4 v = *(const float4*)(h + i);
        ushort4 o;
        o.x = f2bf(v.x); o.y = f2bf(v.y); o.z = f2bf(v.z); o.w = f2bf(v.w);
        *(ushort4*)(hb + i) = o;
    } else if (b < 5120) {
        int bb = b - 4096;
        dev_trans(Wq, bt, 2048, (bb & 31) * 64, (bb >> 5) * 64, t, L);
    } else if (b < 5376) {
        int bb = b - 5120;
        dev_trans(Wk, bt + (size_t)2048 * 2048, 512, (bb & 31) * 64, (bb >> 5) * 64, t, L);
    } else if (b < 5632) {
        int bb = b - 5376;
        dev_trans(Wv, bt + (size_t)2560 * 2048, 512, (bb & 31) * 64, (bb >> 5) * 64, t, L);
    } else if (b < 6656) {
        int bb = b - 5632;
        dev_trans(Wo, wot, 2048, (bb & 31) * 64, (bb >> 5) * 64, t, L);
    } else if (b < 6688) {
        int k0 = (b - 6656) * 64;
        for (int it = 0; it < 4; ++it) {
            int e = it * 256 + t;
            int r = e >> 4, c = e & 15;
            L[c][r] = f2bf(Wf[(size_t)(k0 + r) * 16 + c]);
        }
        __syncthreads();
        unsigned short* dst = bt + (size_t)3072 * 2048;
        for (int it = 0; it < 4; ++it) {
            int e = it * 256 + t;
            int c = e >> 6, kk = e & 63;
            dst[(size_t)c * 2048 + k0 + kk] = L[c][kk];
        }
    } else if (b < 6720) {
        int k0 = (b - 6688) * 64;
        dev_trans(W1, bt + (size_t)3088 * 2048, 64, k0, 0, t, L);
    } else {
        int bb = b - 6720;
        unsigned* p = (unsigned*)(bt + (size_t)3152 * 2048);
        p[bb * 256 + t] = 0u;
    }
}

// ---- merged: fuse (field) + vtrans (vt) ----
__global__ __launch_bounds__(256) void k_fuse_vtrans(const float* __restrict__ adcols,
                        const float* __restrict__ W1, const float* __restrict__ b1,
                        const float* __restrict__ W2, const float* __restrict__ b2,
                        float* __restrict__ field,
                        const unsigned short* __restrict__ vrow, unsigned short* __restrict__ vt) {
    __shared__ unsigned short L[64][65];
    int b = blockIdx.x, t = threadIdx.x;
    if (b < 512) {
        int wv = t >> 6, l = t & 63;
        int s = b * 4 + wv;
        const float* row = adcols + (size_t)s * 128;
        float x = row[16 + l] + b1[l];
#pragma unroll
        for (int f = 0; f < 16; ++f) x += row[f] * W1[(size_t)(2048 + f) * 64 + l];
        float hm = 0.5f * x * (1.f + erff(x * 0.70710678118654752f));
        float p = hm * W2[l];
        for (int m = 32; m; m >>= 1) p += __shfl_xor(p, m);
        if (l == 0) field[s] = 0.005f * (p + b2[0]);
    } else {
        int bb = b - 512;
        int s0 = (bb & 31) * 64, hk = bb >> 5;
        for (int it = 0; it < 16; ++it) {
            int e = it * 256 + t;
            int r = e >> 6, c = e & 63;
            L[c][r] = vrow[(size_t)(s0 + r) * 512 + hk * 64 + c];
        }
        __syncthreads();
        for (int it = 0; it < 16; ++it) {
            int e = it * 256 + t;
            int c = e >> 6, kk = e & 63;
            vt[((size_t)hk * 64 + c) * S_LEN + s0 + KPERM(kk)] = L[c][kk];
        }
    }
}

// ---------------- gate = (field - mean)/(std_ddof1 + 1e-6) ----------------
__global__ void k_gate(const float* __restrict__ field, float* __restrict__ gate) {
    __shared__ float red[256];
    int t = threadIdx.x;
    float s = 0.f;
    for (int i = t; i < S_LEN; i += 256) s += field[i];
    red[t] = s; __syncthreads();
    for (int w = 128; w; w >>= 1) { if (t < w) red[t] += red[t + w]; __syncthreads(); }
    float mean = red[0] / (float)S_LEN;
    __syncthreads();
    float v = 0.f;
    for (int i = t; i < S_LEN; i += 256) { float d = field[i] - mean; v += d * d; }
    red[t] = v; __syncthreads();
    for (int w = 128; w; w >>= 1) { if (t < w) red[t] += red[t + w]; __syncthreads(); }
    float stdv = sqrtf(red[0] / (float)(S_LEN - 1)) + 1e-6f;
    for (int i = t; i < S_LEN; i += 256) gate[i] = (field[i] - mean) / stdv;
}

// ====== shared GEMM core (R17-proven): 64x128 tile, BK=64, swizzled LDS ======
__device__ __forceinline__ void gemm_core(const unsigned short* __restrict__ A,
                                          const unsigned short* __restrict__ BT,
                                          int K, int m0, int n0,
                                          char* As, char* Bs,
                                          int wr, int wc, int lr, int lkb,
                                          f32x4 acc[2][4]) {
    int t = threadIdx.x;
    int wv = t >> 6;
    int srow = t >> 3;
    int scol = 8 * ((t & 7) ^ (srow & 7));
    const unsigned short* Ag = A + (size_t)(m0 + srow) * K + scol;
    const unsigned short* Bg = BT + (size_t)(n0 + srow) * K + scol;
    char* lA = As + wv * 1024;
    char* lB = Bs + wv * 1024;
    int nk = K / 64;
    GLD(Ag, lA); GLD(Ag + (size_t)32 * K, lA + 4096);
    GLD(Bg, lB); GLD(Bg + (size_t)32 * K, lB + 4096);
    GLD(Bg + (size_t)64 * K, lB + 8192); GLD(Bg + (size_t)96 * K, lB + 12288);
    for (int kt = 0; kt < nk; ++kt) {
        __syncthreads();
        bf16x8 af[2][2], bfv[4][2];
#pragma unroll
        for (int i = 0; i < 2; ++i) {
            int row = wr + i * 16 + lr;
#pragma unroll
            for (int kh = 0; kh < 2; ++kh)
                af[i][kh] = *(const bf16x8*)(As + row * 128 + ((kh * 64 + lkb) ^ SWZ(row)));
        }
#pragma unroll
        for (int j = 0; j < 4; ++j) {
            int row = wc + j * 16 + lr;
#pragma unroll
            for (int kh = 0; kh < 2; ++kh)
                bfv[j][kh] = *(const bf16x8*)(Bs + row * 128 + ((kh * 64 + lkb) ^ SWZ(row)));
        }
#pragma unroll
        for (int kh = 0; kh < 2; ++kh)
#pragma unroll
            for (int i = 0; i < 2; ++i)
#pragma unroll
                for (int j = 0; j < 4; ++j)
                    acc[i][j] = __builtin_amdgcn_mfma_f32_16x16x32_bf16(af[i][kh], bfv[j][kh], acc[i][j], 0, 0, 0);
        __syncthreads();
        if (kt + 1 < nk) {
            const unsigned short* Ak = Ag + (size_t)(kt + 1) * 64;
            const unsigned short* Bk = Bg + (size_t)(kt + 1) * 64;
            GLD(Ak, lA); GLD(Ak + (size_t)32 * K, lA + 4096);
            GLD(Bk, lB); GLD(Bk + (size_t)32 * K, lB + 4096);
            GLD(Bk + (size_t)64 * K, lB + 8192); GLD(Bk + (size_t)96 * K, lB + 12288);
        }
    }
}

// ------- GEMM1 (64x128, BK=64, 800 blocks): hb x bt^T + fused RoPE epilogue -------
__global__ __launch_bounds__(256) void k_gemm_qkv(const unsigned short* __restrict__ A,
                                                  const unsigned short* __restrict__ BT,
                                                  const float* __restrict__ cs,
                                                  const float* __restrict__ sn,
                                                  unsigned short* __restrict__ qb,
                                                  unsigned short* __restrict__ kbuf,
                                                  unsigned short* __restrict__ vrow,
                                                  float* __restrict__ adcols) {
    __shared__ __align__(16) char As[8192];
    __shared__ __align__(16) char Bs[16384];
    const int K = 2048;
    int flat = blockIdx.y * gridDim.x + blockIdx.x;
    int cpx = (gridDim.x * gridDim.y) >> 3;
    int swz = (flat & 7) * cpx + (flat >> 3);
    int m0 = (swz / gridDim.x) * 64, n0 = (swz % gridDim.x) * 128;
    int t = threadIdx.x;
    int wv = t >> 6, ln = t & 63;
    int wr = (wv >> 1) * 32, wc = (wv & 1) * 64;
    int lr = ln & 15, lkb = (ln >> 4) * 16;
    f32x4 acc[2][4] = {};
    gemm_core(A, BT, K, m0, n0, As, Bs, wr, wc, lr, lkb, acc);
    int orow = (ln >> 4) * 4;
    int col0 = n0 + wc;
    if (col0 < 2560) {
        bool isq = (col0 < 2048);
        unsigned short* dst = isq ? qb : kbuf;
        int hh = (isq ? col0 : col0 - 2048) >> 6;
        float qscale = isq ? 0.125f : 1.0f;
#pragma unroll
        for (int i = 0; i < 2; ++i)
#pragma unroll
            for (int r = 0; r < 4; ++r) {
                int s = m0 + wr + i * 16 + orow + r;
#pragma unroll
                for (int j = 0; j < 4; ++j) {
                    int d = j * 16 + lr;
                    float c = cs[s * 64 + d], si = sn[s * 64 + d];
                    float val = acc[i][j][r];
                    float prt = acc[i][j ^ 2][r];
                    float out = val * c + ((j < 2) ? -prt : prt) * si;
                    dst[((size_t)hh * S_LEN + s) * 64 + d] = f2bf(out * qscale);
                }
            }
    } else if (col0 < 3072) {
        int vc0 = col0 - 2560;
#pragma unroll
        for (int i = 0; i < 2; ++i)
#pragma unroll
            for (int j = 0; j < 4; ++j) {
                unsigned short* vp = vrow + (size_t)(m0 + wr + i * 16 + orow) * 512 + vc0 + j * 16 + lr;
                for (int r = 0; r < 4; ++r) vp[(size_t)r * 512] = f2bf(acc[i][j][r]);
            }
    } else {
        int ac0 = col0 - 3072;
#pragma unroll
        for (int i = 0; i < 2; ++i)
#pragma unroll
            for (int j = 0; j < 4; ++j) {
                float* ap = adcols + (size_t)(m0 + wr + i * 16 + orow) * 128 + ac0 + j * 16 + lr;
                for (int r = 0; r < 4; ++r) ap[(size_t)r * 128] = acc[i][j][r];
            }
    }
}

// ------- GEMM2 (64x128, BK=64, 512 blocks): C = A x BT^T -------
__global__ __launch_bounds__(256) void k_gemm(const unsigned short* __restrict__ A,
                                              const unsigned short* __restrict__ BT,
                                              float* __restrict__ C, int M, int N, int K) {
    __shared__ __align__(16) char As[8192];
    __shared__ __align__(16) char Bs[16384];
    int flat = blockIdx.y * gridDim.x + blockIdx.x;
    int cpx = (gridDim.x * gridDim.y) >> 3;
    int swz = (flat & 7) * cpx + (flat >> 3);
    int m0 = (swz / gridDim.x) * 64, n0 = (swz % gridDim.x) * 128;
    int t = threadIdx.x;
    int wv = t >> 6, ln = t & 63;
    int wr = (wv >> 1) * 32, wc = (wv & 1) * 64;
    int lr = ln & 15, lkb = (ln >> 4) * 16;
    f32x4 acc[2][4] = {};
    gemm_core(A, BT, K, m0, n0, As, Bs, wr, wc, lr, lkb, acc);
    int orow = (ln >> 4) * 4;
#pragma unroll
    for (int i = 0; i < 2; ++i)
#pragma unroll
        for (int j = 0; j < 4; ++j) {
            float* Cp = C + (size_t)(m0 + wr + i * 16 + orow) * N + n0 + wc + j * 16 + lr;
            for (int r = 0; r < 4; ++r) Cp[(size_t)r * N] = acc[i][j][r];
        }
}

__device__ __forceinline__ bf16x8 packP(const f32x4& a, const f32x4& b) {
    union { unsigned u[4]; bf16x8 v; } pk;
    asm("v_cvt_pk_bf16_f32 %0, %1, %2" : "=v"(pk.u[0]) : "v"(a[0]), "v"(a[1]));
    asm("v_cvt_pk_bf16_f32 %0, %1, %2" : "=v"(pk.u[1]) : "v"(a[2]), "v"(a[3]));
    asm("v_cvt_pk_bf16_f32 %0, %1, %2" : "=v"(pk.u[2]) : "v"(b[0]), "v"(b[1]));
    asm("v_cvt_pk_bf16_f32 %0, %1, %2" : "=v"(pk.u[3]) : "v"(b[2]), "v"(b[3]));
    return pk.v;
}

// ------- flash attention: R14-proven structure + T5 s_setprio on MFMA clusters.
//   Regime matches m191's positive case: small independent blocks at different
//   kt phases per CU -> priority hint lets MFMA-entering waves win issue. -------
__global__ __launch_bounds__(128, 2) void k_attn(const unsigned short* __restrict__ qb,
                                                 const unsigned short* __restrict__ kb,
                                                 const unsigned short* __restrict__ vt,
                                                 const float* __restrict__ gate,
                                                 const float* __restrict__ gs_p,
                                                 unsigned short* __restrict__ attnout) {
    __shared__ __align__(16) char Kl[2][8192];
    __shared__ __align__(16) char Vl[2][8192];
    int h = blockIdx.y, hk = h >> 2;
    int qt = (h < 16) ? (31 - blockIdx.x) : blockIdx.x;
    int t = threadIdx.x, wv = t >> 6, l = t & 63;
    int lq = l & 15, lg = l >> 4;
    float gs = gs_p[0];
    int q0 = qt * 64 + wv * 32;
    const unsigned short* qbase = qb + ((size_t)h * S_LEN + q0) * 64;
    bf16x8 aq[2][2];
#pragma unroll
    for (int qf = 0; qf < 2; ++qf)
#pragma unroll
        for (int hf = 0; hf < 2; ++hf)
            aq[qf][hf] = *(const bf16x8*)(qbase + (qf * 16 + lq) * 64 + hf * 32 + lg * 8);
    f32x4 o[2][4] = {};
    float m_[2] = { -INFINITY, -INFINITY };
    float ls_[2] = { 0.f, 0.f };
    int nkt = qt + 1;
    int srow = t >> 3;
    int scol = 8 * ((t & 7) ^ (srow & 7));
    const unsigned short* kg = kb + (size_t)hk * S_LEN * 64;
    const unsigned short* vg = vt + (size_t)hk * 64 * S_LEN;
    char* lKb0 = Kl[0] + wv * 1024; char* lKb1 = Kl[1] + wv * 1024;
    char* lVb0 = Vl[0] + wv * 1024; char* lVb1 = Vl[1] + wv * 1024;
#define STAGE_KV(K0, DK, DV) do { \
        GLD(kg + (size_t)((K0) + srow) * 64 + scol, (DK)); \
        GLD(kg + (size_t)((K0) + 16 + srow) * 64 + scol, (DK) + 2048); \
        GLD(kg + (size_t)((K0) + 32 + srow) * 64 + scol, (DK) + 4096); \
        GLD(kg + (size_t)((K0) + 48 + srow) * 64 + scol, (DK) + 6144); \
        GLD(vg + (size_t)srow * S_LEN + (K0) + scol, (DV)); \
        GLD(vg + (size_t)(16 + srow) * S_LEN + (K0) + scol, (DV) + 2048); \
        GLD(vg + (size_t)(32 + srow) * S_LEN + (K0) + scol, (DV) + 4096); \
        GLD(vg + (size_t)(48 + srow) * S_LEN + (K0) + scol, (DV) + 6144); \
    } while (0)
    STAGE_KV(0, lKb0, lVb0);
    for (int kt = 0; kt < nkt; ++kt) {
        __syncthreads();
        if (kt + 1 < nkt) {
            int k0n = (kt + 1) * 64;
            char* dK = ((kt + 1) & 1) ? lKb1 : lKb0;
            char* dV = ((kt + 1) & 1) ? lVb1 : lVb0;
            STAGE_KV(k0n, dK, dV);
        }
        int k0 = kt * 64;
        bool diag = (kt == nkt - 1);
        const char* Kb = Kl[kt & 1];
        const char* Vb = Vl[kt & 1];
        // ---- QK^T (T5: elevated priority around MFMA cluster) ----
        f32x4 sc[2][4] = {};
        __builtin_amdgcn_s_setprio(1);
#pragma unroll
        for (int ct = 0; ct < 4; ++ct) {
            int krow = ct * 16 + lq;
#pragma unroll
            for (int hf = 0; hf < 2; ++hf) {
                bf16x8 bk = *(const bf16x8*)(Kb + krow * 128 + ((hf * 64 + lg * 16) ^ SWZ(krow)));
#pragma unroll
                for (int qf = 0; qf < 2; ++qf)
                    sc[qf][ct] = __builtin_amdgcn_mfma_f32_16x16x32_bf16(bk, aq[qf][hf], sc[qf][ct], 0, 0, 0);
            }
        }
        __builtin_amdgcn_s_setprio(0);
        float vmax[2] = { -INFINITY, -INFINITY };
#pragma unroll
        for (int ct = 0; ct < 4; ++ct) {
            f32x4 g4 = *(const f32x4*)(gate + k0 + ct * 16 + lg * 4);
#pragma unroll
            for (int qf = 0; qf < 2; ++qf) {
                int q = q0 + qf * 16 + lq;
#pragma unroll
                for (int r = 0; r < 4; ++r) {
                    float val = sc[qf][ct][r] + gs * g4[r];
                    if (diag && (k0 + ct * 16 + lg * 4 + r > q)) val = -1e9f;
                    sc[qf][ct][r] = val;
                    vmax[qf] = fmaxf(vmax[qf], val);
                }
            }
        }
#pragma unroll
        for (int qf = 0; qf < 2; ++qf) {
            vmax[qf] = fmaxf(vmax[qf], __shfl_xor(vmax[qf], 16));
            vmax[qf] = fmaxf(vmax[qf], __shfl_xor(vmax[qf], 32));
        }
        bool cond = (vmax[0] <= m_[0] + 8.f) && (vmax[1] <= m_[1] + 8.f);
        if (!__all(cond)) {
#pragma unroll
            for (int qf = 0; qf < 2; ++qf) {
                float mn = fmaxf(m_[qf], vmax[qf]);
                float scl = __expf(m_[qf] - mn);
                ls_[qf] *= scl;
#pragma unroll
                for (int dt = 0; dt < 4; ++dt) o[qf][dt] *= scl;
                m_[qf] = mn;
            }
        }
#pragma unroll
        for (int qf = 0; qf < 2; ++qf)
#pragma unroll
            for (int ct = 0; ct < 4; ++ct)
#pragma unroll
                for (int r = 0; r < 4; ++r) {
                    float p = __expf(sc[qf][ct][r] - m_[qf]);
                    sc[qf][ct][r] = p;
                    ls_[qf] += p;
                }
        // ---- PV (T5: elevated priority around MFMA cluster) ----
        __builtin_amdgcn_s_setprio(1);
#pragma unroll
        for (int ks = 0; ks < 2; ++ks) {
            bf16x8 pf0 = packP(sc[0][2 * ks], sc[0][2 * ks + 1]);
            bf16x8 pf1 = packP(sc[1][2 * ks], sc[1][2 * ks + 1]);
#pragma unroll
            for (int dt = 0; dt < 4; ++dt) {
                int vr = dt * 16 + lq;
                bf16x8 bv = *(const bf16x8*)(Vb + vr * 128 + ((ks * 64 + lg * 16) ^ SWZ(vr)));
                o[0][dt] = __builtin_amdgcn_mfma_f32_16x16x32_bf16(bv, pf0, o[0][dt], 0, 0, 0);
                o[1][dt] = __builtin_amdgcn_mfma_f32_16x16x32_bf16(bv, pf1, o[1][dt], 0, 0, 0);
            }
        }
        __builtin_amdgcn_s_setprio(0);
    }
#undef STAGE_KV
#pragma unroll
    for (int qf = 0; qf < 2; ++qf) {
        float s = ls_[qf];
        s += __shfl_xor(s, 16);
        s += __shfl_xor(s, 32);
        float inv = 1.f / s;
        int q = q0 + qf * 16 + lq;
        unsigned short* orow = attnout + (size_t)q * 2048 + h * 64;
#pragma unroll
        for (int dt = 0; dt < 4; ++dt) {
            ushort4 st;
            st.x = f2bf(o[qf][dt][0] * inv); st.y = f2bf(o[qf][dt][1] * inv);
            st.z = f2bf(o[qf][dt][2] * inv); st.w = f2bf(o[qf][dt][3] * inv);
            *(ushort4*)(orow + dt * 16 + lg * 4) = st;
        }
    }
}

extern "C" void kernel_launch(void* const* d_in, const int* in_sizes, int n_in,
                              void* d_out, int out_size, void* d_ws, size_t ws_size,
                              hipStream_t stream) {
    const float* h    = (const float*)d_in[0];
    const float* cosT = (const float*)d_in[2];
    const float* sinT = (const float*)d_in[3];
    const float* Wf   = (const float*)d_in[4];
    const float* W1   = (const float*)d_in[5];
    const float* b1   = (const float*)d_in[6];
    const float* W2   = (const float*)d_in[7];
    const float* b2   = (const float*)d_in[8];
    const float* gs   = (const float*)d_in[9];
    const float* Wq   = (const float*)d_in[10];
    const float* Wk   = (const float*)d_in[11];
    const float* Wv   = (const float*)d_in[12];
    const float* Wo   = (const float*)d_in[13];
    float* out = (float*)d_out;

    char* ws = (char*)d_ws;
    unsigned short* hb     = (unsigned short*)(ws);                // 0..8M      [dead after gemm1]
    unsigned short* bt     = (unsigned short*)(ws + 8388608);      // 8M..21.5M  [dead after gemm1]
    unsigned short* qbuf   = (unsigned short*)(ws + 21495808);     // 8M
    unsigned short* kbuf   = (unsigned short*)(ws + 29884416);     // 2M
    unsigned short* vrow   = (unsigned short*)(ws + 31981568);     // 2M
    float*          adcols = (float*)(ws + 34078720);              // 1M
    float*          field  = (float*)(ws + 35127296);              // 8K
    float*          gate   = (float*)(ws + 35135488);              // 8K
    unsigned short* wot    = (unsigned short*)(ws + 35143680);     // 8M (own slot)
    unsigned short* vt      = (unsigned short*)(ws + 16777216);    // 2M over bt tail
    unsigned short* attnout = (unsigned short*)(ws);               // 8M over hb

    k_prep<<<dim3(6912), dim3(256), 0, stream>>>(h, hb, Wq, Wk, Wv, Wo, Wf, W1, bt, wot);
    k_gemm_qkv<<<dim3(25, 32), dim3(256), 0, stream>>>(hb, bt, cosT, sinT, qbuf, kbuf, vrow, adcols);
    k_fuse_vtrans<<<dim3(768), dim3(256), 0, stream>>>(adcols, W1, b1, W2, b2, field, vrow, vt);
    k_gate<<<dim3(1), dim3(256), 0, stream>>>(field, gate);
    k_attn<<<dim3(32, 32), dim3(128), 0, stream>>>(qbuf, kbuf, vt, gate, gs, attnout);
    k_gemm<<<dim3(16, 32), dim3(256), 0, stream>>>(attnout, wot, out, 2048, 2048, 2048);
}

// Round 22
// 156.213 us; speedup vs baseline: 1.0099x; 1.0099x over previous
//
#include <hip/hip_runtime.h>

#define S_LEN 2048
#define D_DIM 2048
#define NHEAD 32
#define NKVH  8
#define HDIM  64
#define NBT   3200   // 2048 q + 512 k + 512 v + 16 fiber + 64 w1h + 48 pad

typedef __attribute__((ext_vector_type(4))) float f32x4;
typedef __attribute__((ext_vector_type(8))) short bf16x8;

__device__ __forceinline__ unsigned short f2bf(float x) {
    union { float f; unsigned u; } v; v.f = x;
    unsigned r = v.u + 0x7FFFu + ((v.u >> 16) & 1u);
    return (unsigned short)(r >> 16);
}

// async global->LDS 16B: dest = wave-uniform base + lane*16
#define GLD(gsrc, ldst) __builtin_amdgcn_global_load_lds( \
    (const __attribute__((address_space(1))) unsigned int*)(const void*)(gsrc), \
    (__attribute__((address_space(3))) unsigned int*)(void*)(ldst), 16, 0, 0)

#define SWZ(r) (((r) & 7) << 4)

// k-permutation: QK^T C-layout -> PV B-frag consumption (verified R13)
#define KPERM(kk) (((kk) & 32) | (((kk) & 12) << 1) | (((kk) & 16) >> 2) | ((kk) & 3))

// ---- generic 64x64 f32->bf16 transpose tile (into row-stride-2048 dest) ----
__device__ __forceinline__ void dev_trans(const float* __restrict__ W, unsigned short* __restrict__ WT,
                                          int N, int k0, int n0, int t, unsigned short L[64][65]) {
    for (int it = 0; it < 16; ++it) {
        int e = it * 256 + t;
        int r = e >> 6, c = e & 63;
        L[c][r] = f2bf(W[(size_t)(k0 + r) * N + n0 + c]);
    }
    __syncthreads();
    for (int it = 0; it < 16; ++it) {
        int e = it * 256 + t;
        int n = e >> 6, kk = e & 63;
        WT[(size_t)(n0 + n) * 2048 + k0 + kk] = L[n][kk];
    }
}

// ---- merged prep: cvt_h + Wq/Wk/Wv/Wo/Wf/W1 transposes + pad zero ----
__global__ __launch_bounds__(256) void k_prep(const float* __restrict__ h, unsigned short* __restrict__ hb,
        const float* __restrict__ Wq, const float* __restrict__ Wk, const float* __restrict__ Wv,
        const float* __restrict__ Wo, const float* __restrict__ Wf, const float* __restrict__ W1,
        unsigned short* __restrict__ bt, unsigned short* __restrict__ wot) {
    __shared__ unsigned short L[64][65];
    int b = blockIdx.x, t = threadIdx.x;
    if (b < 4096) {
        int i = (b * 256 + t) * 4;
        float4 v = *(const float4*)(h + i);
        ushort4 o;
        o.x = f2bf(v.x); o.y = f2bf(v.y); o.z = f2bf(v.z); o.w = f2bf(v.w);
        *(ushort4*)(hb + i) = o;
    } else if (b < 5120) {
        int bb = b - 4096;
        dev_trans(Wq, bt, 2048, (bb & 31) * 64, (bb >> 5) * 64, t, L);
    } else if (b < 5376) {
        int bb = b - 5120;
        dev_trans(Wk, bt + (size_t)2048 * 2048, 512, (bb & 31) * 64, (bb >> 5) * 64, t, L);
    } else if (b < 5632) {
        int bb = b - 5376;
        dev_trans(Wv, bt + (size_t)2560 * 2048, 512, (bb & 31) * 64, (bb >> 5) * 64, t, L);
    } else if (b < 6656) {
        int bb = b - 5632;
        dev_trans(Wo, wot, 2048, (bb & 31) * 64, (bb >> 5) * 64, t, L);
    } else if (b < 6688) {
        int k0 = (b - 6656) * 64;
        for (int it = 0; it < 4; ++it) {
            int e = it * 256 + t;
            int r = e >> 4, c = e & 15;
            L[c][r] = f2bf(Wf[(size_t)(k0 + r) * 16 + c]);
        }
        __syncthreads();
        unsigned short* dst = bt + (size_t)3072 * 2048;
        for (int it = 0; it < 4; ++it) {
            int e = it * 256 + t;
            int c = e >> 6, kk = e & 63;
            dst[(size_t)c * 2048 + k0 + kk] = L[c][kk];
        }
    } else if (b < 6720) {
        int k0 = (b - 6688) * 64;
        dev_trans(W1, bt + (size_t)3088 * 2048, 64, k0, 0, t, L);
    } else {
        int bb = b - 6720;
        unsigned* p = (unsigned*)(bt + (size_t)3152 * 2048);
        p[bb * 256 + t] = 0u;
    }
}

// ---- merged: fuse (field) + vtrans (vt) ----
__global__ __launch_bounds__(256) void k_fuse_vtrans(const float* __restrict__ adcols,
                        const float* __restrict__ W1, const float* __restrict__ b1,
                        const float* __restrict__ W2, const float* __restrict__ b2,
                        float* __restrict__ field,
                        const unsigned short* __restrict__ vrow, unsigned short* __restrict__ vt) {
    __shared__ unsigned short L[64][65];
    int b = blockIdx.x, t = threadIdx.x;
    if (b < 512) {
        int wv = t >> 6, l = t & 63;
        int s = b * 4 + wv;
        const float* row = adcols + (size_t)s * 128;
        float x = row[16 + l] + b1[l];
#pragma unroll
        for (int f = 0; f < 16; ++f) x += row[f] * W1[(size_t)(2048 + f) * 64 + l];
        float hm = 0.5f * x * (1.f + erff(x * 0.70710678118654752f));
        float p = hm * W2[l];
        for (int m = 32; m; m >>= 1) p += __shfl_xor(p, m);
        if (l == 0) field[s] = 0.005f * (p + b2[0]);
    } else {
        int bb = b - 512;
        int s0 = (bb & 31) * 64, hk = bb >> 5;
        for (int it = 0; it < 16; ++it) {
            int e = it * 256 + t;
            int r = e >> 6, c = e & 63;
            L[c][r] = vrow[(size_t)(s0 + r) * 512 + hk * 64 + c];
        }
        __syncthreads();
        for (int it = 0; it < 16; ++it) {
            int e = it * 256 + t;
            int c = e >> 6, kk = e & 63;
            vt[((size_t)hk * 64 + c) * S_LEN + s0 + KPERM(kk)] = L[c][kk];
        }
    }
}

// ---------------- gate = (field - mean)/(std_ddof1 + 1e-6) ----------------
__global__ void k_gate(const float* __restrict__ field, float* __restrict__ gate) {
    __shared__ float red[256];
    int t = threadIdx.x;
    float s = 0.f;
    for (int i = t; i < S_LEN; i += 256) s += field[i];
    red[t] = s; __syncthreads();
    for (int w = 128; w; w >>= 1) { if (t < w) red[t] += red[t + w]; __syncthreads(); }
    float mean = red[0] / (float)S_LEN;
    __syncthreads();
    float v = 0.f;
    for (int i = t; i < S_LEN; i += 256) { float d = field[i] - mean; v += d * d; }
    red[t] = v; __syncthreads();
    for (int w = 128; w; w >>= 1) { if (t < w) red[t] += red[t + w]; __syncthreads(); }
    float stdv = sqrtf(red[0] / (float)(S_LEN - 1)) + 1e-6f;
    for (int i = t; i < S_LEN; i += 256) gate[i] = (field[i] - mean) / stdv;
}

// ====== shared GEMM core (R17-proven): 64x128 tile, BK=64, swizzled LDS ======
__device__ __forceinline__ void gemm_core(const unsigned short* __restrict__ A,
                                          const unsigned short* __restrict__ BT,
                                          int K, int m0, int n0,
                                          char* As, char* Bs,
                                          int wr, int wc, int lr, int lkb,
                                          f32x4 acc[2][4]) {
    int t = threadIdx.x;
    int wv = t >> 6;
    int srow = t >> 3;
    int scol = 8 * ((t & 7) ^ (srow & 7));
    const unsigned short* Ag = A + (size_t)(m0 + srow) * K + scol;
    const unsigned short* Bg = BT + (size_t)(n0 + srow) * K + scol;
    char* lA = As + wv * 1024;
    char* lB = Bs + wv * 1024;
    int nk = K / 64;
    GLD(Ag, lA); GLD(Ag + (size_t)32 * K, lA + 4096);
    GLD(Bg, lB); GLD(Bg + (size_t)32 * K, lB + 4096);
    GLD(Bg + (size_t)64 * K, lB + 8192); GLD(Bg + (size_t)96 * K, lB + 12288);
    for (int kt = 0; kt < nk; ++kt) {
        __syncthreads();
        bf16x8 af[2][2], bfv[4][2];
#pragma unroll
        for (int i = 0; i < 2; ++i) {
            int row = wr + i * 16 + lr;
#pragma unroll
            for (int kh = 0; kh < 2; ++kh)
                af[i][kh] = *(const bf16x8*)(As + row * 128 + ((kh * 64 + lkb) ^ SWZ(row)));
        }
#pragma unroll
        for (int j = 0; j < 4; ++j) {
            int row = wc + j * 16 + lr;
#pragma unroll
            for (int kh = 0; kh < 2; ++kh)
                bfv[j][kh] = *(const bf16x8*)(Bs + row * 128 + ((kh * 64 + lkb) ^ SWZ(row)));
        }
#pragma unroll
        for (int kh = 0; kh < 2; ++kh)
#pragma unroll
            for (int i = 0; i < 2; ++i)
#pragma unroll
                for (int j = 0; j < 4; ++j)
                    acc[i][j] = __builtin_amdgcn_mfma_f32_16x16x32_bf16(af[i][kh], bfv[j][kh], acc[i][j], 0, 0, 0);
        __syncthreads();
        if (kt + 1 < nk) {
            const unsigned short* Ak = Ag + (size_t)(kt + 1) * 64;
            const unsigned short* Bk = Bg + (size_t)(kt + 1) * 64;
            GLD(Ak, lA); GLD(Ak + (size_t)32 * K, lA + 4096);
            GLD(Bk, lB); GLD(Bk + (size_t)32 * K, lB + 4096);
            GLD(Bk + (size_t)64 * K, lB + 8192); GLD(Bk + (size_t)96 * K, lB + 12288);
        }
    }
}

// ------- GEMM1 (64x128, BK=64, 800 blocks): hb x bt^T + fused RoPE epilogue -------
__global__ __launch_bounds__(256) void k_gemm_qkv(const unsigned short* __restrict__ A,
                                                  const unsigned short* __restrict__ BT,
                                                  const float* __restrict__ cs,
                                                  const float* __restrict__ sn,
                                                  unsigned short* __restrict__ qb,
                                                  unsigned short* __restrict__ kbuf,
                                                  unsigned short* __restrict__ vrow,
                                                  float* __restrict__ adcols) {
    __shared__ __align__(16) char As[8192];
    __shared__ __align__(16) char Bs[16384];
    const int K = 2048;
    int flat = blockIdx.y * gridDim.x + blockIdx.x;
    int cpx = (gridDim.x * gridDim.y) >> 3;
    int swz = (flat & 7) * cpx + (flat >> 3);
    int m0 = (swz / gridDim.x) * 64, n0 = (swz % gridDim.x) * 128;
    int t = threadIdx.x;
    int wv = t >> 6, ln = t & 63;
    int wr = (wv >> 1) * 32, wc = (wv & 1) * 64;
    int lr = ln & 15, lkb = (ln >> 4) * 16;
    f32x4 acc[2][4] = {};
    gemm_core(A, BT, K, m0, n0, As, Bs, wr, wc, lr, lkb, acc);
    int orow = (ln >> 4) * 4;
    int col0 = n0 + wc;
    if (col0 < 2560) {
        bool isq = (col0 < 2048);
        unsigned short* dst = isq ? qb : kbuf;
        int hh = (isq ? col0 : col0 - 2048) >> 6;
        float qscale = isq ? 0.125f : 1.0f;
#pragma unroll
        for (int i = 0; i < 2; ++i)
#pragma unroll
            for (int r = 0; r < 4; ++r) {
                int s = m0 + wr + i * 16 + orow + r;
#pragma unroll
                for (int j = 0; j < 4; ++j) {
                    int d = j * 16 + lr;
                    float c = cs[s * 64 + d], si = sn[s * 64 + d];
                    float val = acc[i][j][r];
                    float prt = acc[i][j ^ 2][r];
                    float out = val * c + ((j < 2) ? -prt : prt) * si;
                    dst[((size_t)hh * S_LEN + s) * 64 + d] = f2bf(out * qscale);
                }
            }
    } else if (col0 < 3072) {
        int vc0 = col0 - 2560;
#pragma unroll
        for (int i = 0; i < 2; ++i)
#pragma unroll
            for (int j = 0; j < 4; ++j) {
                unsigned short* vp = vrow + (size_t)(m0 + wr + i * 16 + orow) * 512 + vc0 + j * 16 + lr;
                for (int r = 0; r < 4; ++r) vp[(size_t)r * 512] = f2bf(acc[i][j][r]);
            }
    } else {
        int ac0 = col0 - 3072;
#pragma unroll
        for (int i = 0; i < 2; ++i)
#pragma unroll
            for (int j = 0; j < 4; ++j) {
                float* ap = adcols + (size_t)(m0 + wr + i * 16 + orow) * 128 + ac0 + j * 16 + lr;
                for (int r = 0; r < 4; ++r) ap[(size_t)r * 128] = acc[i][j][r];
            }
    }
}

// ------- GEMM2 (64x128, BK=64, 512 blocks): C = A x BT^T -------
__global__ __launch_bounds__(256) void k_gemm(const unsigned short* __restrict__ A,
                                              const unsigned short* __restrict__ BT,
                                              float* __restrict__ C, int M, int N, int K) {
    __shared__ __align__(16) char As[8192];
    __shared__ __align__(16) char Bs[16384];
    int flat = blockIdx.y * gridDim.x + blockIdx.x;
    int cpx = (gridDim.x * gridDim.y) >> 3;
    int swz = (flat & 7) * cpx + (flat >> 3);
    int m0 = (swz / gridDim.x) * 64, n0 = (swz % gridDim.x) * 128;
    int t = threadIdx.x;
    int wv = t >> 6, ln = t & 63;
    int wr = (wv >> 1) * 32, wc = (wv & 1) * 64;
    int lr = ln & 15, lkb = (ln >> 4) * 16;
    f32x4 acc[2][4] = {};
    gemm_core(A, BT, K, m0, n0, As, Bs, wr, wc, lr, lkb, acc);
    int orow = (ln >> 4) * 4;
#pragma unroll
    for (int i = 0; i < 2; ++i)
#pragma unroll
        for (int j = 0; j < 4; ++j) {
            float* Cp = C + (size_t)(m0 + wr + i * 16 + orow) * N + n0 + wc + j * 16 + lr;
            for (int r = 0; r < 4; ++r) Cp[(size_t)r * N] = acc[i][j][r];
        }
}

__device__ __forceinline__ bf16x8 packP(const f32x4& a, const f32x4& b) {
    union { unsigned u[4]; bf16x8 v; } pk;
    asm("v_cvt_pk_bf16_f32 %0, %1, %2" : "=v"(pk.u[0]) : "v"(a[0]), "v"(a[1]));
    asm("v_cvt_pk_bf16_f32 %0, %1, %2" : "=v"(pk.u[1]) : "v"(a[2]), "v"(a[3]));
    asm("v_cvt_pk_bf16_f32 %0, %1, %2" : "=v"(pk.u[2]) : "v"(b[0]), "v"(b[1]));
    asm("v_cvt_pk_bf16_f32 %0, %1, %2" : "=v"(pk.u[3]) : "v"(b[2]), "v"(b[3]));
    return pk.v;
}

// ------- flash attention: R14-proven (swapped QK^T, in-register P, 2-wave blocks,
//         KVBLK=64, dbuf GLD staging, balanced qt pairing) — final build -------
__global__ __launch_bounds__(128, 2) void k_attn(const unsigned short* __restrict__ qb,
                                                 const unsigned short* __restrict__ kb,
                                                 const unsigned short* __restrict__ vt,
                                                 const float* __restrict__ gate,
                                                 const float* __restrict__ gs_p,
                                                 unsigned short* __restrict__ attnout) {
    __shared__ __align__(16) char Kl[2][8192];
    __shared__ __align__(16) char Vl[2][8192];
    int h = blockIdx.y, hk = h >> 2;
    int qt = (h < 16) ? (31 - blockIdx.x) : blockIdx.x;
    int t = threadIdx.x, wv = t >> 6, l = t & 63;
    int lq = l & 15, lg = l >> 4;
    float gs = gs_p[0];
    int q0 = qt * 64 + wv * 32;
    const unsigned short* qbase = qb + ((size_t)h * S_LEN + q0) * 64;
    bf16x8 aq[2][2];
#pragma unroll
    for (int qf = 0; qf < 2; ++qf)
#pragma unroll
        for (int hf = 0; hf < 2; ++hf)
            aq[qf][hf] = *(const bf16x8*)(qbase + (qf * 16 + lq) * 64 + hf * 32 + lg * 8);
    f32x4 o[2][4] = {};
    float m_[2] = { -INFINITY, -INFINITY };
    float ls_[2] = { 0.f, 0.f };
    int nkt = qt + 1;
    int srow = t >> 3;
    int scol = 8 * ((t & 7) ^ (srow & 7));
    const unsigned short* kg = kb + (size_t)hk * S_LEN * 64;
    const unsigned short* vg = vt + (size_t)hk * 64 * S_LEN;
    char* lKb0 = Kl[0] + wv * 1024; char* lKb1 = Kl[1] + wv * 1024;
    char* lVb0 = Vl[0] + wv * 1024; char* lVb1 = Vl[1] + wv * 1024;
#define STAGE_KV(K0, DK, DV) do { \
        GLD(kg + (size_t)((K0) + srow) * 64 + scol, (DK)); \
        GLD(kg + (size_t)((K0) + 16 + srow) * 64 + scol, (DK) + 2048); \
        GLD(kg + (size_t)((K0) + 32 + srow) * 64 + scol, (DK) + 4096); \
        GLD(kg + (size_t)((K0) + 48 + srow) * 64 + scol, (DK) + 6144); \
        GLD(vg + (size_t)srow * S_LEN + (K0) + scol, (DV)); \
        GLD(vg + (size_t)(16 + srow) * S_LEN + (K0) + scol, (DV) + 2048); \
        GLD(vg + (size_t)(32 + srow) * S_LEN + (K0) + scol, (DV) + 4096); \
        GLD(vg + (size_t)(48 + srow) * S_LEN + (K0) + scol, (DV) + 6144); \
    } while (0)
    STAGE_KV(0, lKb0, lVb0);
    for (int kt = 0; kt < nkt; ++kt) {
        __syncthreads();
        if (kt + 1 < nkt) {
            int k0n = (kt + 1) * 64;
            char* dK = ((kt + 1) & 1) ? lKb1 : lKb0;
            char* dV = ((kt + 1) & 1) ? lVb1 : lVb0;
            STAGE_KV(k0n, dK, dV);
        }
        int k0 = kt * 64;
        bool diag = (kt == nkt - 1);
        const char* Kb = Kl[kt & 1];
        const char* Vb = Vl[kt & 1];
        f32x4 sc[2][4] = {};
#pragma unroll
        for (int ct = 0; ct < 4; ++ct) {
            int krow = ct * 16 + lq;
#pragma unroll
            for (int hf = 0; hf < 2; ++hf) {
                bf16x8 bk = *(const bf16x8*)(Kb + krow * 128 + ((hf * 64 + lg * 16) ^ SWZ(krow)));
#pragma unroll
                for (int qf = 0; qf < 2; ++qf)
                    sc[qf][ct] = __builtin_amdgcn_mfma_f32_16x16x32_bf16(bk, aq[qf][hf], sc[qf][ct], 0, 0, 0);
            }
        }
        float vmax[2] = { -INFINITY, -INFINITY };
#pragma unroll
        for (int ct = 0; ct < 4; ++ct) {
            f32x4 g4 = *(const f32x4*)(gate + k0 + ct * 16 + lg * 4);
#pragma unroll
            for (int qf = 0; qf < 2; ++qf) {
                int q = q0 + qf * 16 + lq;
#pragma unroll
                for (int r = 0; r < 4; ++r) {
                    float val = sc[qf][ct][r] + gs * g4[r];
                    if (diag && (k0 + ct * 16 + lg * 4 + r > q)) val = -1e9f;
                    sc[qf][ct][r] = val;
                    vmax[qf] = fmaxf(vmax[qf], val);
                }
            }
        }
#pragma unroll
        for (int qf = 0; qf < 2; ++qf) {
            vmax[qf] = fmaxf(vmax[qf], __shfl_xor(vmax[qf], 16));
            vmax[qf] = fmaxf(vmax[qf], __shfl_xor(vmax[qf], 32));
        }
        bool cond = (vmax[0] <= m_[0] + 8.f) && (vmax[1] <= m_[1] + 8.f);
        if (!__all(cond)) {
#pragma unroll
            for (int qf = 0; qf < 2; ++qf) {
                float mn = fmaxf(m_[qf], vmax[qf]);
                float scl = __expf(m_[qf] - mn);
                ls_[qf] *= scl;
#pragma unroll
                for (int dt = 0; dt < 4; ++dt) o[qf][dt] *= scl;
                m_[qf] = mn;
            }
        }
#pragma unroll
        for (int qf = 0; qf < 2; ++qf)
#pragma unroll
            for (int ct = 0; ct < 4; ++ct)
#pragma unroll
                for (int r = 0; r < 4; ++r) {
                    float p = __expf(sc[qf][ct][r] - m_[qf]);
                    sc[qf][ct][r] = p;
                    ls_[qf] += p;
                }
#pragma unroll
        for (int ks = 0; ks < 2; ++ks) {
            bf16x8 pf0 = packP(sc[0][2 * ks], sc[0][2 * ks + 1]);
            bf16x8 pf1 = packP(sc[1][2 * ks], sc[1][2 * ks + 1]);
#pragma unroll
            for (int dt = 0; dt < 4; ++dt) {
                int vr = dt * 16 + lq;
                bf16x8 bv = *(const bf16x8*)(Vb + vr * 128 + ((ks * 64 + lg * 16) ^ SWZ(vr)));
                o[0][dt] = __builtin_amdgcn_mfma_f32_16x16x32_bf16(bv, pf0, o[0][dt], 0, 0, 0);
                o[1][dt] = __builtin_amdgcn_mfma_f32_16x16x32_bf16(bv, pf1, o[1][dt], 0, 0, 0);
            }
        }
    }
#undef STAGE_KV
#pragma unroll
    for (int qf = 0; qf < 2; ++qf) {
        float s = ls_[qf];
        s += __shfl_xor(s, 16);
        s += __shfl_xor(s, 32);
        float inv = 1.f / s;
        int q = q0 + qf * 16 + lq;
        unsigned short* orow = attnout + (size_t)q * 2048 + h * 64;
#pragma unroll
        for (int dt = 0; dt < 4; ++dt) {
            ushort4 st;
            st.x = f2bf(o[qf][dt][0] * inv); st.y = f2bf(o[qf][dt][1] * inv);
            st.z = f2bf(o[qf][dt][2] * inv); st.w = f2bf(o[qf][dt][3] * inv);
            *(ushort4*)(orow + dt * 16 + lg * 4) = st;
        }
    }
}

extern "C" void kernel_launch(void* const* d_in, const int* in_sizes, int n_in,
                              void* d_out, int out_size, void* d_ws, size_t ws_size,
                              hipStream_t stream) {
    const float* h    = (const float*)d_in[0];
    const float* cosT = (const float*)d_in[2];
    const float* sinT = (const float*)d_in[3];
    const float* Wf   = (const float*)d_in[4];
    const float* W1   = (const float*)d_in[5];
    const float* b1   = (const float*)d_in[6];
    const float* W2   = (const float*)d_in[7];
    const float* b2   = (const float*)d_in[8];
    const float* gs   = (const float*)d_in[9];
    const float* Wq   = (const float*)d_in[10];
    const float* Wk   = (const float*)d_in[11];
    const float* Wv   = (const float*)d_in[12];
    const float* Wo   = (const float*)d_in[13];
    float* out = (float*)d_out;

    char* ws = (char*)d_ws;
    unsigned short* hb     = (unsigned short*)(ws);                // 0..8M      [dead after gemm1]
    unsigned short* bt     = (unsigned short*)(ws + 8388608);      // 8M..21.5M  [dead after gemm1]
    unsigned short* qbuf   = (unsigned short*)(ws + 21495808);     // 8M
    unsigned short* kbuf   = (unsigned short*)(ws + 29884416);     // 2M
    unsigned short* vrow   = (unsigned short*)(ws + 31981568);     // 2M
    float*          adcols = (float*)(ws + 34078720);              // 1M
    float*          field  = (float*)(ws + 35127296);              // 8K
    float*          gate   = (float*)(ws + 35135488);              // 8K
    unsigned short* wot    = (unsigned short*)(ws + 35143680);     // 8M (own slot)
    unsigned short* vt      = (unsigned short*)(ws + 16777216);    // 2M over bt tail
    unsigned short* attnout = (unsigned short*)(ws);               // 8M over hb

    k_prep<<<dim3(6912), dim3(256), 0, stream>>>(h, hb, Wq, Wk, Wv, Wo, Wf, W1, bt, wot);
    k_gemm_qkv<<<dim3(25, 32), dim3(256), 0, stream>>>(hb, bt, cosT, sinT, qbuf, kbuf, vrow, adcols);
    k_fuse_vtrans<<<dim3(768), dim3(256), 0, stream>>>(adcols, W1, b1, W2, b2, field, vrow, vt);
    k_gate<<<dim3(1), dim3(256), 0, stream>>>(field, gate);
    k_attn<<<dim3(32, 32), dim3(128), 0, stream>>>(qbuf, kbuf, vt, gate, gs, attnout);
    k_gemm<<<dim3(16, 32), dim3(256), 0, stream>>>(attnout, wot, out, 2048, 2048, 2048);
}